// Round 4
// baseline (251.654 us; speedup 1.0000x reference)
//
#include <hip/hip_runtime.h>
#include <hip/hip_bf16.h>

#define EPS 1e-5f

// ---------- bf16 helpers (RNE) ----------
__device__ __forceinline__ unsigned short f2bf(float f) {
    unsigned int u = __builtin_bit_cast(unsigned int, f);
    unsigned int r = u + 0x7FFFu + ((u >> 16) & 1u);
    return (unsigned short)(r >> 16);
}
__device__ __forceinline__ unsigned int pk2bf(float a, float b) {
    return (unsigned int)f2bf(a) | ((unsigned int)f2bf(b) << 16);
}
__device__ __forceinline__ float bf2f(unsigned short b) {
    unsigned int u = ((unsigned int)b) << 16;
    return __builtin_bit_cast(float, u);
}
__device__ __forceinline__ float bflo(unsigned int u) {   // low ushort of dword
    return __builtin_bit_cast(float, u << 16);
}
__device__ __forceinline__ float bfhi(unsigned int u) {   // high ushort of dword
    return __builtin_bit_cast(float, u & 0xFFFF0000u);
}

typedef __attribute__((ext_vector_type(8))) short short8;   // 8 bf16 (4 VGPRs)
typedef __attribute__((ext_vector_type(4))) float floatx4;  // MFMA accumulator

// w pre-cast to bf16 once per launch (128 KB static device buffer).
__device__ unsigned short g_wbf[256 * 256];

__global__ __launch_bounds__(256) void wcast(const float* __restrict__ w) {
    int i = (blockIdx.x * 256 + threadIdx.x) * 4;
    float4 v = *reinterpret_cast<const float4*>(w + i);
    *reinterpret_cast<ushort4*>(&g_wbf[i]) =
        make_ushort4(f2bf(v.x), f2bf(v.y), f2bf(v.z), f2bf(v.w));
}

// =====================================================================
// Kernel A v4: y = relu(bn(conv1x1(x)))  -> bf16 workspace
//   BARRIER-FREE k-loop:
//   - A frags read directly from g_wbf (global, L2-hot; no LDS, no stage)
//   - B (x^T) staged into WAVE-PRIVATE LDS [kq][px][kk] (dbuf, 4 KB/wave):
//     each wave loads its own 64 px x 32 k, converts, writes, reads —
//     no __syncthreads in the loop (wave LDS ops are program-ordered).
//     Layout gives uniform 8 dwords/bank on both ds_write_b128 and the
//     short8 frag reads (pure-BW, conflict-free).
//   Waves drift independently -> HBM load issue is continuous, not
//   barrier-gated bursts.
// =====================================================================
__global__ __launch_bounds__(256, 3) void conv1x1_bn_relu(
    const float* __restrict__ x,
    const float* __restrict__ cb,
    const float* __restrict__ gamma, const float* __restrict__ beta,
    const float* __restrict__ mean,  const float* __restrict__ var,
    unsigned short* __restrict__ y)
{
    const int nt  = blockIdx.x >> 1;   // pixel tile 0..79
    const int mb  = blockIdx.x & 1;    // channel tile (adjacent for L2 reuse)
    const int b   = blockIdx.z;
    const int tid = threadIdx.x;

    // per-wave private B staging: [wave][dbuf][kq][px][kk]  (32 KB)
    __shared__ unsigned short Bw[4][2][4][64][8];
    __shared__ float s1[128], u1[128];

    const int m0 = mb * 128;
    const int p0 = nt * 128;

    if (tid < 128) {
        int o = m0 + tid;
        float s = gamma[o] * rsqrtf(var[o] + EPS);
        s1[tid] = s;
        u1[tid] = cb[o] * s + beta[o] - mean[o] * s;
    }

    const int lane = tid & 63;
    const int wv   = tid >> 6;
    const int wm   = (wv & 1) * 64;
    const int wn   = (wv >> 1) * 64;
    const int lm   = lane & 15;
    const int lq   = lane >> 4;

    // this lane's pixel column in x (k-major walk down the column)
    const float* xp = x + (size_t)b * 256 * 10240 + p0 + wn + lane;
    // this lane's A-frag base in bf16 weights
    const unsigned short* wp = g_wbf + (size_t)(m0 + wm + lm) * 256 + lq * 8;

    floatx4 acc[4][4];
#pragma unroll
    for (int i = 0; i < 4; i++)
#pragma unroll
        for (int j = 0; j < 4; j++) acc[i][j] = (floatx4)0.0f;

    float xr[32];

#define LOADX(T)                                                             \
    {                                                                        \
        _Pragma("unroll")                                                    \
        for (int k = 0; k < 32; k++)                                         \
            xr[k] = xp[(size_t)((T) * 32 + k) * 10240];                      \
    }
#define WRITEX(BUF)                                                          \
    {                                                                        \
        _Pragma("unroll")                                                    \
        for (int kq = 0; kq < 4; kq++) {                                     \
            uint4 pk;                                                        \
            pk.x = pk2bf(xr[kq * 8 + 0], xr[kq * 8 + 1]);                    \
            pk.y = pk2bf(xr[kq * 8 + 2], xr[kq * 8 + 3]);                    \
            pk.z = pk2bf(xr[kq * 8 + 4], xr[kq * 8 + 5]);                    \
            pk.w = pk2bf(xr[kq * 8 + 6], xr[kq * 8 + 7]);                    \
            *reinterpret_cast<uint4*>(&Bw[wv][BUF][kq][lane][0]) = pk;       \
        }                                                                    \
    }

    LOADX(0);
    WRITEX(0);

#pragma unroll
    for (int t = 0; t < 8; t++) {
        if (t < 7) LOADX(t + 1);           // issue next tile's loads EARLY

        short8 af[4], bfr[4];
#pragma unroll
        for (int i = 0; i < 4; i++)
            af[i] = *reinterpret_cast<const short8*>(wp + i * 16 * 256 + t * 32);
#pragma unroll
        for (int j = 0; j < 4; j++)
            bfr[j] = *reinterpret_cast<const short8*>(
                &Bw[wv][t & 1][lq][j * 16 + lm][0]);
#pragma unroll
        for (int i = 0; i < 4; i++)
#pragma unroll
            for (int j = 0; j < 4; j++)
                acc[i][j] = __builtin_amdgcn_mfma_f32_16x16x32_bf16(
                    af[i], bfr[j], acc[i][j], 0, 0, 0);

        if (t < 7) WRITEX((t + 1) & 1);
    }

#undef LOADX
#undef WRITEX

    __syncthreads();                       // s1/u1 visible (only barrier)

    unsigned short* yb = y + (size_t)b * 256 * 10240;
#pragma unroll
    for (int i = 0; i < 4; i++) {
        int mo_base = wm + i * 16 + lq * 4;
#pragma unroll
        for (int j = 0; j < 4; j++) {
            int p = p0 + wn + j * 16 + lm;
#pragma unroll
            for (int r = 0; r < 4; r++) {
                int mo = mo_base + r;
                float v = acc[i][j][r] * s1[mo] + u1[mo];
                v = fmaxf(v, 0.0f);
                yb[(size_t)(m0 + mo) * 10240 + p] = f2bf(v);
            }
        }
    }
}

// =====================================================================
// Kernel B v2.1 (unchanged): one block per (b,c) — full 64x160 image.
// =====================================================================
#define YTS 176   // yt stride (ushorts) = 88 dwords, 352 B
#define QTS 168   // qt stride (floats), 672 B
#define W1f 0.80073740f
#define W2f 0.41111229f
#define W3f 0.13533528f
#define RSCALE (0.5f / (4.0f * (W1f + W2f + W3f)))

__global__ __launch_bounds__(512, 4) void refine_accum(
    const float* __restrict__ x,
    const unsigned short* __restrict__ y,
    const float* __restrict__ rw,
    const float* __restrict__ rb,
    const float* __restrict__ rg, const float* __restrict__ rbe,
    const float* __restrict__ rm, const float* __restrict__ rv,
    float* __restrict__ out)
{
    const int c   = blockIdx.x & 255;
    const int b   = blockIdx.x >> 8;
    const int tid = threadIdx.x;

    __shared__ __align__(16) unsigned short yt[64 * YTS];   // 22528 B
    __shared__ __align__(16) float qt[64 * QTS];            // 43008 B
    __shared__ __align__(16) float q_top[7 * QTS];          //  4704 B
    __shared__ __align__(16) float q_bot[7 * QTS];          //  4704 B
    __shared__ __align__(16) float q_lr[2][64 * 8];         //  4096 B
    __shared__ float cfixq[48];                             //   192 B

    const size_t img = ((size_t)b * 256 + c) * 10240;
    const unsigned short* yp = y + img;

    float w9[9];
#pragma unroll
    for (int t = 0; t < 9; t++) w9[t] = rw[c * 9 + t];
    const float s2 = rg[c] * rsqrtf(rv[c] + EPS);
    const float u2 = rb[c] * s2 + rbe[c] - rm[c] * s2;

    // ---- P1: stage y (raw bf16). Main body: 16B vector copies.
    {
        unsigned int* yd = reinterpret_cast<unsigned int*>(yt);
        for (int t = tid; t < 1280; t += 512) {
            int r = t / 20, u = t - r * 20;            // chunk u: w = 8u..8u+7
            uint4 v = *reinterpret_cast<const uint4*>(yp + r * 160 + u * 8);
            int base = r * 88 + 4 * u + 3;             // dword idx of col 8u+6
            yd[base]     = v.x;
            yd[base + 1] = v.y;
            yd[base + 2] = v.z;
            yd[base + 3] = v.w;
        }
        // wrap cols: j 0..5 <-> w 154..159 ; j 166..171 <-> w 0..5
        for (int t = tid; t < 768; t += 512) {
            int r = t / 12, k = t - r * 12;
            int w = (k < 6) ? 154 + k : k - 6;
            int j = (k < 6) ? k : 160 + k;
            yt[r * YTS + j] = yp[r * 160 + w];
        }
    }
    __syncthreads();

    // ---- P2a: qt = relu(bn(circular 3x3 conv)), incl. 4-col halo each side.
    {
        const unsigned int* yd = reinterpret_cast<const unsigned int*>(yt);
        for (int t = tid; t < 672; t += 512) {
            int rg0 = t / 42, G = t - rg0 * 42;
            int r0 = rg0 * 4;
            float yc[6][8];
#pragma unroll
            for (int k = 0; k < 6; k++) {
                int rr = (r0 + k + 63) & 63;           // rows r0-1 .. r0+4
                uint2 lo = *reinterpret_cast<const uint2*>(yd + rr * 88 + 2 * G);
                uint2 hi = *reinterpret_cast<const uint2*>(yd + rr * 88 + 2 * G + 2);
                yc[k][0] = bflo(lo.x); yc[k][1] = bfhi(lo.x);
                yc[k][2] = bflo(lo.y); yc[k][3] = bfhi(lo.y);
                yc[k][4] = bflo(hi.x); yc[k][5] = bfhi(hi.x);
                yc[k][6] = bflo(hi.y); yc[k][7] = bfhi(hi.y);
            }
#pragma unroll
            for (int k = 0; k < 4; k++) {
                floatx4 qv;
#pragma unroll
                for (int cc = 0; cc < 4; cc++) {
                    float z = 0.f;
#pragma unroll
                    for (int dh = 0; dh < 3; dh++)
#pragma unroll
                        for (int dw = 0; dw < 3; dw++)
                            z += w9[dh * 3 + dw] * yc[k + dh][cc + 1 + dw];
                    qv[cc] = fmaxf(z * s2 + u2, 0.f);
                }
                *reinterpret_cast<floatx4*>(&qt[(r0 + k) * QTS + 4 * G]) = qv;
            }
        }

        // ---- P2b: q_top (kernel top row masked) rows {61..63,0..3},
        //           q_bot (bottom row masked)     rows {60..63,0..2}.
        for (int t = tid; t < 588; t += 512) {
            int v  = t >= 294;
            int tt = t - 294 * v;
            int i = tt / 42, G = tt - i * 42;
            int row0 = (v ? (59 + i) : (61 + i)) & 63;
            int row1 = (row0 + 1) & 63;
            int wb = v ? 0 : 3;
            float a0[8], a1[8];
            {
                uint2 lo = *reinterpret_cast<const uint2*>(yd + row0 * 88 + 2 * G);
                uint2 hi = *reinterpret_cast<const uint2*>(yd + row0 * 88 + 2 * G + 2);
                a0[0] = bflo(lo.x); a0[1] = bfhi(lo.x); a0[2] = bflo(lo.y); a0[3] = bfhi(lo.y);
                a0[4] = bflo(hi.x); a0[5] = bfhi(hi.x); a0[6] = bflo(hi.y); a0[7] = bfhi(hi.y);
            }
            {
                uint2 lo = *reinterpret_cast<const uint2*>(yd + row1 * 88 + 2 * G);
                uint2 hi = *reinterpret_cast<const uint2*>(yd + row1 * 88 + 2 * G + 2);
                a1[0] = bflo(lo.x); a1[1] = bfhi(lo.x); a1[2] = bflo(lo.y); a1[3] = bfhi(lo.y);
                a1[4] = bflo(hi.x); a1[5] = bfhi(hi.x); a1[6] = bflo(hi.y); a1[7] = bfhi(hi.y);
            }
            float* dst = v ? q_bot : q_top;
            floatx4 qv;
#pragma unroll
            for (int cc = 0; cc < 4; cc++) {
                float z = 0.f;
#pragma unroll
                for (int dw = 0; dw < 3; dw++)
                    z += w9[wb + dw] * a0[cc + 1 + dw]
                       + w9[wb + 3 + dw] * a1[cc + 1 + dw];
                qv[cc] = fmaxf(z * s2 + u2, 0.f);
            }
            *reinterpret_cast<floatx4*>(&dst[i * QTS + 4 * G]) = qv;
        }
    }

    // ---- P2c: q_left/q_right + P2d corner taps.
    if (tid < 224) {
        int v  = tid >= 112;
        int tt = tid - 112 * v;
        int rg0 = tt / 7, i = tt - rg0 * 7;
        int r0 = rg0 * 4;
        int col0 = v ? (155 + i) : (157 + i);          // first unmasked y col
        if (col0 >= 160) col0 -= 160;
        int j0 = col0 + 6;
        int wbase = v ? 0 : 1;
        float pa[6], pb[6];
#pragma unroll
        for (int k = 0; k < 6; k++) {
            int rr = (r0 + k + 63) & 63;
            pa[k] = bf2f(yt[rr * YTS + j0]);
            pb[k] = bf2f(yt[rr * YTS + j0 + 1]);
        }
#pragma unroll
        for (int k = 0; k < 4; k++) {
            float z = 0.f;
#pragma unroll
            for (int dh = 0; dh < 3; dh++)
                z += w9[dh * 3 + wbase] * pa[k + dh]
                   + w9[dh * 3 + wbase + 1] * pb[k + dh];
            q_lr[v][(r0 + k) * 8 + i] = fmaxf(z * s2 + u2, 0.f);
        }
    } else if (tid >= 464) {
        int t = tid - 464;                              // 0..47
        int kk = t / 12, s = t - kk * 12;
        int h = (kk & 1) ? 63 : 0;
        int w = (kk & 2) ? 159 : 0;
        int sh = (s < 3) ? (s + 1) : ((s < 6) ? -(s - 2) : 0);
        int sw = (s < 6) ? 0 : ((s < 9) ? -(s - 5) : (s - 8));
        int rr = (h - sh) & 63;
        int cc = (w - sw + 160) % 160;
        float z = 0.f;
#pragma unroll
        for (int dh = 0; dh < 3; dh++)
#pragma unroll
            for (int dw = 0; dw < 3; dw++) {
                int ih = h + dh - 1, iw = w + dw - 1;
                if (ih >= 0 && ih < 64 && iw >= 0 && iw < 160) {
                    int ry = (rr + dh - 1) & 63;
                    int jy = cc + dw + 5;               // cc+dw-1+6, in [5,166]
                    z += w9[dh * 3 + dw] * bf2f(yt[ry * YTS + jy]);
                }
            }
        cfixq[t] = fmaxf(z * s2 + u2, 0.f);
    }
    __syncthreads();

    // ---- P3: uniform 12-tap accumulate, 4-row register blocking.
    for (int t = tid; t < 640; t += 512) {
        int rg0 = t / 40, g = t - rg0 * 40;
        int r0 = rg0 * 4;
        int jq = 4 * g + 4;
        floatx4 vq[10];
#pragma unroll
        for (int k = 0; k < 10; k++)                   // q rows r0-3 .. r0+6
            vq[k] = *reinterpret_cast<const floatx4*>(
                &qt[((r0 + k + 61) & 63) * QTS + jq]);
#pragma unroll
        for (int k = 0; k < 4; k++) {
            int r = r0 + k;
            floatx4 hl = *reinterpret_cast<const floatx4*>(&qt[r * QTS + jq - 4]);
            floatx4 hr = *reinterpret_cast<const floatx4*>(&qt[r * QTS + jq + 4]);
            float H[12];
#pragma unroll
            for (int q = 0; q < 4; q++) { H[q] = hl[q]; H[4 + q] = vq[k + 3][q]; H[8 + q] = hr[q]; }
            floatx4 xv = *reinterpret_cast<const floatx4*>(
                &x[img + (size_t)r * 160 + 4 * g]);
            floatx4 ov;
#pragma unroll
            for (int cc = 0; cc < 4; cc++) {
                float vs = W1f * (vq[k + 2][cc] + vq[k + 4][cc])
                         + W2f * (vq[k + 1][cc] + vq[k + 5][cc])
                         + W3f * (vq[k][cc]     + vq[k + 6][cc]);
                float hs = W1f * (H[3 + cc] + H[5 + cc])
                         + W2f * (H[2 + cc] + H[6 + cc])
                         + W3f * (H[1 + cc] + H[7 + cc]);
                ov[cc] = xv[cc] + RSCALE * (vs + hs);
            }
            *reinterpret_cast<floatx4*>(&out[img + (size_t)r * 160 + 4 * g]) = ov;
        }
    }
    __syncthreads();

    // ---- P4: overwrite the 444 border pixels with exact masked values.
    if (tid < 444) {
        float acc = 0.f;
        int h_, w_;
        if (tid < 316) {                                // rows 0 and 63, w=1..158
            int v = tid >= 158;
            w_ = 1 + (tid - 158 * v);
            h_ = v ? 63 : 0;
            const float* arr = v ? q_bot : q_top;
#pragma unroll
            for (int s = 0; s < 12; s++) {
                int sh = (s < 3) ? (s + 1) : ((s < 6) ? -(s - 2) : 0);
                int sw = (s < 6) ? 0 : ((s < 9) ? -(s - 5) : (s - 8));
                int d  = s % 3;
                float wt = (d == 0) ? W1f : ((d == 1) ? W2f : W3f);
                acc += wt * arr[(3 - sh) * QTS + (w_ - sw + 4)];
            }
        } else if (tid < 440) {                         // cols 0 and 159, h=1..62
            int v = tid >= 378;
            h_ = 1 + (tid - 316 - 62 * v);
            w_ = v ? 159 : 0;
            const float* arr = q_lr[v];
#pragma unroll
            for (int s = 0; s < 12; s++) {
                int sh = (s < 3) ? (s + 1) : ((s < 6) ? -(s - 2) : 0);
                int sw = (s < 6) ? 0 : ((s < 9) ? -(s - 5) : (s - 8));
                int d  = s % 3;
                float wt = (d == 0) ? W1f : ((d == 1) ? W2f : W3f);
                acc += wt * arr[((h_ - sh) & 63) * 8 + (3 - sw)];
            }
        } else {                                        // 4 corners (tid 440..443)
            int kk = tid - 440;
            h_ = (kk & 1) ? 63 : 0;
            w_ = (kk & 2) ? 159 : 0;
#pragma unroll
            for (int s = 0; s < 12; s++) {
                int d = s % 3;
                float wt = (d == 0) ? W1f : ((d == 1) ? W2f : W3f);
                acc += wt * cfixq[kk * 12 + s];
            }
        }
        size_t gi = img + (size_t)h_ * 160 + w_;
        out[gi] = x[gi] + RSCALE * acc;
    }
}

extern "C" void kernel_launch(void* const* d_in, const int* in_sizes, int n_in,
                              void* d_out, int out_size, void* d_ws, size_t ws_size,
                              hipStream_t stream) {
    const float* x      = (const float*)d_in[0];
    const float* conv_w = (const float*)d_in[1];
    const float* conv_b = (const float*)d_in[2];
    const float* bn_g   = (const float*)d_in[3];
    const float* bn_b   = (const float*)d_in[4];
    const float* bn_m   = (const float*)d_in[5];
    const float* bn_v   = (const float*)d_in[6];
    const float* ref_w  = (const float*)d_in[7];
    const float* ref_b  = (const float*)d_in[8];
    const float* rbn_g  = (const float*)d_in[9];
    const float* rbn_b  = (const float*)d_in[10];
    const float* rbn_m  = (const float*)d_in[11];
    const float* rbn_v  = (const float*)d_in[12];
    float* out          = (float*)d_out;
    unsigned short* y_ws = (unsigned short*)d_ws;  // bf16 y: 41.9 MB

    wcast<<<dim3(64), 256, 0, stream>>>(conv_w);
    conv1x1_bn_relu<<<dim3(160, 1, 8), 256, 0, stream>>>(
        x, conv_b, bn_g, bn_b, bn_m, bn_v, y_ws);
    refine_accum<<<dim3(2048), 512, 0, stream>>>(
        x, y_ws, ref_w, ref_b, rbn_g, rbn_b, rbn_m, rbn_v, out);
}

// Round 6
// 230.583 us; speedup vs baseline: 1.0914x; 1.0914x over previous
//
#include <hip/hip_runtime.h>
#include <hip/hip_bf16.h>

#define EPS 1e-5f

// ---------- bf16 helpers ----------
__device__ __forceinline__ float bf2f(unsigned short b) {
    unsigned int u = ((unsigned int)b) << 16;
    return __builtin_bit_cast(float, u);
}
__device__ __forceinline__ float bflo(unsigned int u) {   // low ushort of dword
    return __builtin_bit_cast(float, u << 16);
}
__device__ __forceinline__ float bfhi(unsigned int u) {   // high ushort of dword
    return __builtin_bit_cast(float, u & 0xFFFF0000u);
}
// native converts via union pun (class types aren't trivially copyable)
__device__ __forceinline__ unsigned short nbf(float f) {
    union { __hip_bfloat16 h; unsigned short u; } c;
    c.h = __float2bfloat16(f);
    return c.u;
}
__device__ __forceinline__ unsigned int cvtpk(float a, float b) {
    return (unsigned int)nbf(a) | ((unsigned int)nbf(b) << 16);
}

typedef __attribute__((ext_vector_type(8))) short short8;   // 8 bf16 (4 VGPRs)
typedef __attribute__((ext_vector_type(4))) float floatx4;  // MFMA accumulator

// =====================================================================
// Kernel A v5.1: y = relu(bn(conv1x1(x)))  -> bf16 workspace
//   T3/T4-lite pipeline:
//   - raw s_barrier + lgkmcnt(0) only (NO vmcnt drain) once per k-step
//   - next k-tile's global loads issued BEFORE the LDS write of the
//     current prefetch -> compiler emits counted vmcnt; loads stay in
//     flight across the barrier (the thing __syncthreads forbids)
//   - x loaded as float2 (8 B/lane), w as float4
//   - B LDS layout [kq][slot][8] with slot = (px&1)*64 + px/2:
//     both ds_write_b128 (consecutive lanes -> consecutive 16B) and
//     frag ds_read_b128 are bank-uniform.
// =====================================================================
#define SK 40

__global__ __launch_bounds__(256) void conv1x1_bn_relu(
    const float* __restrict__ x,
    const float* __restrict__ w,
    const float* __restrict__ cb,
    const float* __restrict__ gamma, const float* __restrict__ beta,
    const float* __restrict__ mean,  const float* __restrict__ var,
    unsigned short* __restrict__ y)
{
    const int nt  = blockIdx.x >> 1;   // pixel tile 0..79
    const int mb  = blockIdx.x & 1;    // channel tile (adjacent for L2 reuse)
    const int b   = blockIdx.z;
    const int tid = threadIdx.x;

    __shared__ unsigned short Al[2][128 * SK];      // 20480 B
    __shared__ unsigned short Bl[2][4][128][8];     // 16384 B
    __shared__ float s1[128], u1[128];

    const int m0 = mb * 128;
    const int p0 = nt * 128;

    if (tid < 128) {
        int o = m0 + tid;
        float s = gamma[o] * rsqrtf(var[o] + EPS);
        s1[tid] = s;
        u1[tid] = cb[o] * s + beta[o] - mean[o] * s;
    }

    const float* xb = x + (size_t)b * 256 * 10240;

    floatx4 acc[4][4];
#pragma unroll
    for (int i = 0; i < 4; i++)
#pragma unroll
        for (int j = 0; j < 4; j++) acc[i][j] = (floatx4)0.0f;

    const int lane = tid & 63;
    const int wv   = tid >> 6;
    const int wm   = (wv & 1) * 64;
    const int wn   = (wv >> 1) * 64;
    const int lm   = lane & 15;
    const int lq   = lane >> 4;

    // B staging: thread -> (k-group, pixel pair)
    const int px2 = tid & 63;          // pixel pair index (px = 2*px2, 2*px2+1)
    const int kg  = tid >> 6;          // k-group 0..3 (k = kg*8 + i)
    // A staging: thread -> (row base, k-quad)
    const int am  = tid >> 3;          // row 0..31 (+32 per it)
    const int af4 = tid & 7;           // k-quad 0..7

    float4 wa[2][4];                   // prefetched w (16 fp32)
    float2 xr[2][8];                   // prefetched x (8 px-pairs over k)

#define LOADA(S, K0)                                                          \
    {                                                                         \
        _Pragma("unroll")                                                     \
        for (int it = 0; it < 4; it++)                                        \
            wa[S][it] = *reinterpret_cast<const float4*>(                     \
                w + (size_t)(m0 + am + it * 32) * 256 + (K0) + af4 * 4);      \
    }
#define LOADB(S, K0)                                                          \
    {                                                                         \
        _Pragma("unroll")                                                     \
        for (int i = 0; i < 8; i++)                                           \
            xr[S][i] = *reinterpret_cast<const float2*>(                      \
                xb + (size_t)((K0) + kg * 8 + i) * 10240 + p0 + px2 * 2);     \
    }
#define WRITEA(S, BUF)                                                        \
    {                                                                         \
        _Pragma("unroll")                                                     \
        for (int it = 0; it < 4; it++) {                                      \
            uint2 u;                                                          \
            u.x = cvtpk(wa[S][it].x, wa[S][it].y);                            \
            u.y = cvtpk(wa[S][it].z, wa[S][it].w);                            \
            *reinterpret_cast<uint2*>(&Al[BUF][(am + it * 32) * SK + af4 * 4]) = u; \
        }                                                                     \
    }
#define WRITEB(S, BUF)                                                        \
    {                                                                         \
        uint4 e, o;                                                           \
        e.x = cvtpk(xr[S][0].x, xr[S][1].x);                                  \
        e.y = cvtpk(xr[S][2].x, xr[S][3].x);                                  \
        e.z = cvtpk(xr[S][4].x, xr[S][5].x);                                  \
        e.w = cvtpk(xr[S][6].x, xr[S][7].x);                                  \
        o.x = cvtpk(xr[S][0].y, xr[S][1].y);                                  \
        o.y = cvtpk(xr[S][2].y, xr[S][3].y);                                  \
        o.z = cvtpk(xr[S][4].y, xr[S][5].y);                                  \
        o.w = cvtpk(xr[S][6].y, xr[S][7].y);                                  \
        *reinterpret_cast<uint4*>(&Bl[BUF][kg][px2][0])      = e;             \
        *reinterpret_cast<uint4*>(&Bl[BUF][kg][64 + px2][0]) = o;             \
    }
#define PIPE_BARRIER()                                                        \
    {                                                                         \
        asm volatile("s_waitcnt lgkmcnt(0)" ::: "memory");                    \
        __builtin_amdgcn_s_barrier();                                         \
        __builtin_amdgcn_sched_barrier(0);                                    \
    }

    // ---- prologue: tile0 -> buf0, issue tile1 loads (stay in flight)
    LOADA(0, 0); LOADB(0, 0);
    WRITEA(0, 0); WRITEB(0, 0);
    LOADA(1, 32); LOADB(1, 32);
    PIPE_BARRIER();

#pragma unroll
    for (int t = 0; t < 8; t++) {
        const int cur = t & 1;

        short8 afr[4], bfr[4];
#pragma unroll
        for (int i = 0; i < 4; i++) {
            int m = wm + i * 16 + lm;
            afr[i] = *reinterpret_cast<const short8*>(&Al[cur][m * SK + lq * 8]);
        }
#pragma unroll
        for (int j = 0; j < 4; j++) {
            int n  = wn + j * 16 + lm;
            int sl = ((n & 1) << 6) | (n >> 1);
            bfr[j] = *reinterpret_cast<const short8*>(&Bl[cur][lq][sl][0]);
        }
#pragma unroll
        for (int i = 0; i < 4; i++)
#pragma unroll
            for (int j = 0; j < 4; j++)
                acc[i][j] = __builtin_amdgcn_mfma_f32_16x16x32_bf16(
                    afr[i], bfr[j], acc[i][j], 0, 0, 0);

        if (t < 7) {
            if (t < 6) {                       // issue tile t+2 (set 'cur' is free)
                LOADA(cur, (t + 2) * 32);
                LOADB(cur, (t + 2) * 32);
            }
            // write tile t+1 (counted vmcnt wait: t+2 loads stay in flight)
            WRITEA(cur ^ 1, cur ^ 1);
            WRITEB(cur ^ 1, cur ^ 1);
            PIPE_BARRIER();
        }
    }

#undef LOADA
#undef LOADB
#undef WRITEA
#undef WRITEB
#undef PIPE_BARRIER

    // s1/u1 visibility was established by the prologue barrier.
    unsigned short* yb = y + (size_t)b * 256 * 10240;
#pragma unroll
    for (int i = 0; i < 4; i++) {
        int mo_base = wm + i * 16 + lq * 4;
#pragma unroll
        for (int j = 0; j < 4; j++) {
            int p = p0 + wn + j * 16 + lm;
#pragma unroll
            for (int r = 0; r < 4; r++) {
                int mo = mo_base + r;
                float v = acc[i][j][r] * s1[mo] + u1[mo];
                v = fmaxf(v, 0.0f);
                yb[(size_t)(m0 + mo) * 10240 + p] = nbf(v);
            }
        }
    }
}

// =====================================================================
// Kernel B v2.1 (unchanged): one block per (b,c) — full 64x160 image.
// =====================================================================
#define YTS 176   // yt stride (ushorts) = 88 dwords, 352 B
#define QTS 168   // qt stride (floats), 672 B
#define W1f 0.80073740f
#define W2f 0.41111229f
#define W3f 0.13533528f
#define RSCALE (0.5f / (4.0f * (W1f + W2f + W3f)))

__global__ __launch_bounds__(512, 4) void refine_accum(
    const float* __restrict__ x,
    const unsigned short* __restrict__ y,
    const float* __restrict__ rw,
    const float* __restrict__ rb,
    const float* __restrict__ rg, const float* __restrict__ rbe,
    const float* __restrict__ rm, const float* __restrict__ rv,
    float* __restrict__ out)
{
    const int c   = blockIdx.x & 255;
    const int b   = blockIdx.x >> 8;
    const int tid = threadIdx.x;

    __shared__ __align__(16) unsigned short yt[64 * YTS];   // 22528 B
    __shared__ __align__(16) float qt[64 * QTS];            // 43008 B
    __shared__ __align__(16) float q_top[7 * QTS];          //  4704 B
    __shared__ __align__(16) float q_bot[7 * QTS];          //  4704 B
    __shared__ __align__(16) float q_lr[2][64 * 8];         //  4096 B
    __shared__ float cfixq[48];                             //   192 B

    const size_t img = ((size_t)b * 256 + c) * 10240;
    const unsigned short* yp = y + img;

    float w9[9];
#pragma unroll
    for (int t = 0; t < 9; t++) w9[t] = rw[c * 9 + t];
    const float s2 = rg[c] * rsqrtf(rv[c] + EPS);
    const float u2 = rb[c] * s2 + rbe[c] - rm[c] * s2;

    // ---- P1: stage y (raw bf16). Main body: 16B vector copies.
    {
        unsigned int* yd = reinterpret_cast<unsigned int*>(yt);
        for (int t = tid; t < 1280; t += 512) {
            int r = t / 20, u = t - r * 20;            // chunk u: w = 8u..8u+7
            uint4 v = *reinterpret_cast<const uint4*>(yp + r * 160 + u * 8);
            int base = r * 88 + 4 * u + 3;             // dword idx of col 8u+6
            yd[base]     = v.x;
            yd[base + 1] = v.y;
            yd[base + 2] = v.z;
            yd[base + 3] = v.w;
        }
        // wrap cols: j 0..5 <-> w 154..159 ; j 166..171 <-> w 0..5
        for (int t = tid; t < 768; t += 512) {
            int r = t / 12, k = t - r * 12;
            int w = (k < 6) ? 154 + k : k - 6;
            int j = (k < 6) ? k : 160 + k;
            yt[r * YTS + j] = yp[r * 160 + w];
        }
    }
    __syncthreads();

    // ---- P2a: qt = relu(bn(circular 3x3 conv)), incl. 4-col halo each side.
    {
        const unsigned int* yd = reinterpret_cast<const unsigned int*>(yt);
        for (int t = tid; t < 672; t += 512) {
            int rg0 = t / 42, G = t - rg0 * 42;
            int r0 = rg0 * 4;
            float yc[6][8];
#pragma unroll
            for (int k = 0; k < 6; k++) {
                int rr = (r0 + k + 63) & 63;           // rows r0-1 .. r0+4
                uint2 lo = *reinterpret_cast<const uint2*>(yd + rr * 88 + 2 * G);
                uint2 hi = *reinterpret_cast<const uint2*>(yd + rr * 88 + 2 * G + 2);
                yc[k][0] = bflo(lo.x); yc[k][1] = bfhi(lo.x);
                yc[k][2] = bflo(lo.y); yc[k][3] = bfhi(lo.y);
                yc[k][4] = bflo(hi.x); yc[k][5] = bfhi(hi.x);
                yc[k][6] = bflo(hi.y); yc[k][7] = bfhi(hi.y);
            }
#pragma unroll
            for (int k = 0; k < 4; k++) {
                floatx4 qv;
#pragma unroll
                for (int cc = 0; cc < 4; cc++) {
                    float z = 0.f;
#pragma unroll
                    for (int dh = 0; dh < 3; dh++)
#pragma unroll
                        for (int dw = 0; dw < 3; dw++)
                            z += w9[dh * 3 + dw] * yc[k + dh][cc + 1 + dw];
                    qv[cc] = fmaxf(z * s2 + u2, 0.f);
                }
                *reinterpret_cast<floatx4*>(&qt[(r0 + k) * QTS + 4 * G]) = qv;
            }
        }

        // ---- P2b: q_top (kernel top row masked) rows {61..63,0..3},
        //           q_bot (bottom row masked)     rows {60..63,0..2}.
        for (int t = tid; t < 588; t += 512) {
            int v  = t >= 294;
            int tt = t - 294 * v;
            int i = tt / 42, G = tt - i * 42;
            int row0 = (v ? (59 + i) : (61 + i)) & 63;
            int row1 = (row0 + 1) & 63;
            int wb = v ? 0 : 3;
            float a0[8], a1[8];
            {
                uint2 lo = *reinterpret_cast<const uint2*>(yd + row0 * 88 + 2 * G);
                uint2 hi = *reinterpret_cast<const uint2*>(yd + row0 * 88 + 2 * G + 2);
                a0[0] = bflo(lo.x); a0[1] = bfhi(lo.x); a0[2] = bflo(lo.y); a0[3] = bfhi(lo.y);
                a0[4] = bflo(hi.x); a0[5] = bfhi(hi.x); a0[6] = bflo(hi.y); a0[7] = bfhi(hi.y);
            }
            {
                uint2 lo = *reinterpret_cast<const uint2*>(yd + row1 * 88 + 2 * G);
                uint2 hi = *reinterpret_cast<const uint2*>(yd + row1 * 88 + 2 * G + 2);
                a1[0] = bflo(lo.x); a1[1] = bfhi(lo.x); a1[2] = bflo(lo.y); a1[3] = bfhi(lo.y);
                a1[4] = bflo(hi.x); a1[5] = bfhi(hi.x); a1[6] = bflo(hi.y); a1[7] = bfhi(hi.y);
            }
            float* dst = v ? q_bot : q_top;
            floatx4 qv;
#pragma unroll
            for (int cc = 0; cc < 4; cc++) {
                float z = 0.f;
#pragma unroll
                for (int dw = 0; dw < 3; dw++)
                    z += w9[wb + dw] * a0[cc + 1 + dw]
                       + w9[wb + 3 + dw] * a1[cc + 1 + dw];
                qv[cc] = fmaxf(z * s2 + u2, 0.f);
            }
            *reinterpret_cast<floatx4*>(&dst[i * QTS + 4 * G]) = qv;
        }
    }

    // ---- P2c: q_left/q_right + P2d corner taps.
    if (tid < 224) {
        int v  = tid >= 112;
        int tt = tid - 112 * v;
        int rg0 = tt / 7, i = tt - rg0 * 7;
        int r0 = rg0 * 4;
        int col0 = v ? (155 + i) : (157 + i);          // first unmasked y col
        if (col0 >= 160) col0 -= 160;
        int j0 = col0 + 6;
        int wbase = v ? 0 : 1;
        float pa[6], pb[6];
#pragma unroll
        for (int k = 0; k < 6; k++) {
            int rr = (r0 + k + 63) & 63;
            pa[k] = bf2f(yt[rr * YTS + j0]);
            pb[k] = bf2f(yt[rr * YTS + j0 + 1]);
        }
#pragma unroll
        for (int k = 0; k < 4; k++) {
            float z = 0.f;
#pragma unroll
            for (int dh = 0; dh < 3; dh++)
                z += w9[dh * 3 + wbase] * pa[k + dh]
                   + w9[dh * 3 + wbase + 1] * pb[k + dh];
            q_lr[v][(r0 + k) * 8 + i] = fmaxf(z * s2 + u2, 0.f);
        }
    } else if (tid >= 464) {
        int t = tid - 464;                              // 0..47
        int kk = t / 12, s = t - kk * 12;
        int h = (kk & 1) ? 63 : 0;
        int w = (kk & 2) ? 159 : 0;
        int sh = (s < 3) ? (s + 1) : ((s < 6) ? -(s - 2) : 0);
        int sw = (s < 6) ? 0 : ((s < 9) ? -(s - 5) : (s - 8));
        int rr = (h - sh) & 63;
        int cc = (w - sw + 160) % 160;
        float z = 0.f;
#pragma unroll
        for (int dh = 0; dh < 3; dh++)
#pragma unroll
            for (int dw = 0; dw < 3; dw++) {
                int ih = h + dh - 1, iw = w + dw - 1;
                if (ih >= 0 && ih < 64 && iw >= 0 && iw < 160) {
                    int ry = (rr + dh - 1) & 63;
                    int jy = cc + dw + 5;               // cc+dw-1+6, in [5,166]
                    z += w9[dh * 3 + dw] * bf2f(yt[ry * YTS + jy]);
                }
            }
        cfixq[t] = fmaxf(z * s2 + u2, 0.f);
    }
    __syncthreads();

    // ---- P3: uniform 12-tap accumulate, 4-row register blocking.
    for (int t = tid; t < 640; t += 512) {
        int rg0 = t / 40, g = t - rg0 * 40;
        int r0 = rg0 * 4;
        int jq = 4 * g + 4;
        floatx4 vq[10];
#pragma unroll
        for (int k = 0; k < 10; k++)                   // q rows r0-3 .. r0+6
            vq[k] = *reinterpret_cast<const floatx4*>(
                &qt[((r0 + k + 61) & 63) * QTS + jq]);
#pragma unroll
        for (int k = 0; k < 4; k++) {
            int r = r0 + k;
            floatx4 hl = *reinterpret_cast<const floatx4*>(&qt[r * QTS + jq - 4]);
            floatx4 hr = *reinterpret_cast<const floatx4*>(&qt[r * QTS + jq + 4]);
            float H[12];
#pragma unroll
            for (int q = 0; q < 4; q++) { H[q] = hl[q]; H[4 + q] = vq[k + 3][q]; H[8 + q] = hr[q]; }
            floatx4 xv = *reinterpret_cast<const floatx4*>(
                &x[img + (size_t)r * 160 + 4 * g]);
            floatx4 ov;
#pragma unroll
            for (int cc = 0; cc < 4; cc++) {
                float vs = W1f * (vq[k + 2][cc] + vq[k + 4][cc])
                         + W2f * (vq[k + 1][cc] + vq[k + 5][cc])
                         + W3f * (vq[k][cc]     + vq[k + 6][cc]);
                float hs = W1f * (H[3 + cc] + H[5 + cc])
                         + W2f * (H[2 + cc] + H[6 + cc])
                         + W3f * (H[1 + cc] + H[7 + cc]);
                ov[cc] = xv[cc] + RSCALE * (vs + hs);
            }
            *reinterpret_cast<floatx4*>(&out[img + (size_t)r * 160 + 4 * g]) = ov;
        }
    }
    __syncthreads();

    // ---- P4: overwrite the 444 border pixels with exact masked values.
    if (tid < 444) {
        float acc = 0.f;
        int h_, w_;
        if (tid < 316) {                                // rows 0 and 63, w=1..158
            int v = tid >= 158;
            w_ = 1 + (tid - 158 * v);
            h_ = v ? 63 : 0;
            const float* arr = v ? q_bot : q_top;
#pragma unroll
            for (int s = 0; s < 12; s++) {
                int sh = (s < 3) ? (s + 1) : ((s < 6) ? -(s - 2) : 0);
                int sw = (s < 6) ? 0 : ((s < 9) ? -(s - 5) : (s - 8));
                int d  = s % 3;
                float wt = (d == 0) ? W1f : ((d == 1) ? W2f : W3f);
                acc += wt * arr[(3 - sh) * QTS + (w_ - sw + 4)];
            }
        } else if (tid < 440) {                         // cols 0 and 159, h=1..62
            int v = tid >= 378;
            h_ = 1 + (tid - 316 - 62 * v);
            w_ = v ? 159 : 0;
            const float* arr = q_lr[v];
#pragma unroll
            for (int s = 0; s < 12; s++) {
                int sh = (s < 3) ? (s + 1) : ((s < 6) ? -(s - 2) : 0);
                int sw = (s < 6) ? 0 : ((s < 9) ? -(s - 5) : (s - 8));
                int d  = s % 3;
                float wt = (d == 0) ? W1f : ((d == 1) ? W2f : W3f);
                acc += wt * arr[((h_ - sh) & 63) * 8 + (3 - sw)];
            }
        } else {                                        // 4 corners (tid 440..443)
            int kk = tid - 440;
            h_ = (kk & 1) ? 63 : 0;
            w_ = (kk & 2) ? 159 : 0;
#pragma unroll
            for (int s = 0; s < 12; s++) {
                int d = s % 3;
                float wt = (d == 0) ? W1f : ((d == 1) ? W2f : W3f);
                acc += wt * cfixq[kk * 12 + s];
            }
        }
        size_t gi = img + (size_t)h_ * 160 + w_;
        out[gi] = x[gi] + RSCALE * acc;
    }
}

extern "C" void kernel_launch(void* const* d_in, const int* in_sizes, int n_in,
                              void* d_out, int out_size, void* d_ws, size_t ws_size,
                              hipStream_t stream) {
    const float* x      = (const float*)d_in[0];
    const float* conv_w = (const float*)d_in[1];
    const float* conv_b = (const float*)d_in[2];
    const float* bn_g   = (const float*)d_in[3];
    const float* bn_b   = (const float*)d_in[4];
    const float* bn_m   = (const float*)d_in[5];
    const float* bn_v   = (const float*)d_in[6];
    const float* ref_w  = (const float*)d_in[7];
    const float* ref_b  = (const float*)d_in[8];
    const float* rbn_g  = (const float*)d_in[9];
    const float* rbn_b  = (const float*)d_in[10];
    const float* rbn_m  = (const float*)d_in[11];
    const float* rbn_v  = (const float*)d_in[12];
    float* out          = (float*)d_out;
    unsigned short* y_ws = (unsigned short*)d_ws;  // bf16 y: 41.9 MB

    conv1x1_bn_relu<<<dim3(160, 1, 8), 256, 0, stream>>>(
        x, conv_w, conv_b, bn_g, bn_b, bn_m, bn_v, y_ws);
    refine_accum<<<dim3(2048), 512, 0, stream>>>(
        x, y_ws, ref_w, ref_b, rbn_g, rbn_b, rbn_m, rbn_v, out);
}